// Round 3
// baseline (6011.374 us; speedup 1.0000x reference)
//
#include <hip/hip_runtime.h>

#define NLAYER 12
#define NHEAD  12
#define DHEAD  64
#define DMODEL 768
#define SEQL   65
#define NBATCH 256
#define MTOK   (NBATCH*SEQL)   // 16640
#define MLPD   3072

typedef _Float16 f16;
typedef f16  f16x8 __attribute__((ext_vector_type(8)));
typedef f16  f16x4 __attribute__((ext_vector_type(4)));
typedef float f32x4 __attribute__((ext_vector_type(4)));

#define MFMA(a,b,c) __builtin_amdgcn_mfma_f32_16x16x32_f16(a,b,c,0,0,0)

__device__ __forceinline__ void gload16(const void* g, void* l) {
  __builtin_amdgcn_global_load_lds((const __attribute__((address_space(1))) void*)g,
                                   (__attribute__((address_space(3))) void*)l, 16, 0, 0);
}

// ---------------- fp32 -> fp16 convert ----------------
__global__ __launch_bounds__(256) void cvt_f16k(const float* __restrict__ in,
                                                f16* __restrict__ out, int n) {
  long i = ((long)blockIdx.x*256 + threadIdx.x)*4;
  if (i >= n) return;
  const float4 v = *(const float4*)(in + i);
  f16x4 o = { (f16)v.x, (f16)v.y, (f16)v.z, (f16)v.w };
  *(f16x4*)(out + i) = o;
}

// ---------------- patch embed + cls + pos ----------------
__global__ __launch_bounds__(256) void patch_embed(
    const float* __restrict__ images, const float* __restrict__ lw,
    const float* __restrict__ lb, const float* __restrict__ cls,
    const float* __restrict__ pe, float* __restrict__ x) {
  const int s = blockIdx.x, n = blockIdx.y, tid = threadIdx.x;
  __shared__ float p[16];
  if (s > 0 && tid < 16) p[tid] = images[(long)n*1024 + (s-1)*16 + tid];
  __syncthreads();
  float* xr = x + ((long)n*SEQL + s)*DMODEL;
  #pragma unroll
  for (int j = 0; j < 3; ++j) {
    int d = tid + j*256;
    float v;
    if (s == 0) {
      v = cls[d] + pe[d];
    } else {
      float acc = lb[d];
      #pragma unroll
      for (int i = 0; i < 16; ++i) acc += p[i]*lw[d*16+i];
      v = acc + pe[s*DMODEL + d];
    }
    xr[d] = v;
  }
}

// ---------------- LayerNorm (fp32 in, fp16 out) ----------------
__global__ __launch_bounds__(256) void ln_kernel(
    const float* __restrict__ x, const float* __restrict__ g,
    const float* __restrict__ b, f16* __restrict__ out) {
  const int row = blockIdx.x, tid = threadIdx.x;
  const float* xr = x + (long)row*DMODEL;
  float v0 = xr[tid], v1 = xr[tid+256], v2 = xr[tid+512];
  float s = v0+v1+v2;
  float s2 = v0*v0 + v1*v1 + v2*v2;
  #pragma unroll
  for (int o = 32; o >= 1; o >>= 1) { s += __shfl_xor(s, o); s2 += __shfl_xor(s2, o); }
  __shared__ float red[8];
  const int wave = tid>>6, lane = tid&63;
  if (lane == 0) { red[wave] = s; red[4+wave] = s2; }
  __syncthreads();
  s  = red[0]+red[1]+red[2]+red[3];
  s2 = red[4]+red[5]+red[6]+red[7];
  float mean = s * (1.f/768.f);
  float var  = s2 * (1.f/768.f) - mean*mean;
  float rstd = rsqrtf(var + 1e-5f);
  f16* orow = out + (long)row*DMODEL;
  orow[tid]     = (f16)((v0-mean)*rstd*g[tid]     + b[tid]);
  orow[tid+256] = (f16)((v1-mean)*rstd*g[tid+256] + b[tid+256]);
  orow[tid+512] = (f16)((v2-mean)*rstd*g[tid+512] + b[tid+512]);
}

// ---------------- fused per-(b,head) QKV + attention, x += o ----------------
__global__ __launch_bounds__(256) void attn_kernel(
    const f16* __restrict__ h, const f16* __restrict__ wq, const f16* __restrict__ wk,
    const f16* __restrict__ wv, const float* __restrict__ bq, const float* __restrict__ bk,
    const float* __restrict__ bv, float* __restrict__ x) {
  __shared__ __align__(16) f16 HsPs[80*104];
  __shared__ __align__(16) f16 Qs[80*72];
  __shared__ __align__(16) f16 Ks[80*72];
  __shared__ __align__(16) f16 Vt[64*104];
  const int hd = blockIdx.x, b = blockIdx.y;
  const int tid = threadIdx.x, wave = tid>>6, lane = tid&63;
  const int lc = lane & 15, lg = lane >> 4;
  const f16* hbase = h + ((long)b*SEQL)*DMODEL + hd*DHEAD;

  for (int c = tid; c < 80*8; c += 256) {
    int s = c >> 3, ec = (c & 7)*8;
    uint4 val = {0u,0u,0u,0u};
    if (s < SEQL) val = *(const uint4*)(hbase + (long)s*DMODEL + ec);
    *(uint4*)&HsPs[s*104 + ec] = val;
  }
  for (int c = tid; c < 64*104/8; c += 256) {
    uint4 z = {0u,0u,0u,0u};
    *(uint4*)&Vt[c*8] = z;
  }
  __syncthreads();

  for (int task = wave; task < 15; task += 4) {
    int mat = task / 5, mt = task % 5;
    const f16* W = (mat == 0 ? wq : mat == 1 ? wk : wv) + hd*DHEAD*DHEAD;
    const float* bias = (mat == 0 ? bq : mat == 1 ? bk : bv) + hd*DHEAD;
    #pragma unroll
    for (int nt = 0; nt < 4; ++nt) {
      f32x4 a = {0.f,0.f,0.f,0.f};
      #pragma unroll
      for (int kt = 0; kt < 2; ++kt) {
        f16x8 af = *(const f16x8*)&HsPs[(mt*16 + lc)*104 + kt*32 + lg*8];
        f16x8 bf = *(const f16x8*)&W[(nt*16 + lc)*DHEAD + kt*32 + lg*8];
        a = MFMA(af, bf, a);
      }
      float bb = bias[nt*16 + lc];
      #pragma unroll
      for (int r = 0; r < 4; ++r) {
        int s = mt*16 + lg*4 + r;
        int e = nt*16 + lc;
        float v = a[r] + bb;
        if (mat == 0)      Qs[s*72 + e] = (f16)v;
        else if (mat == 1) Ks[s*72 + e] = (f16)v;
        else               Vt[e*104 + s] = (f16)v;
      }
    }
  }
  __syncthreads();

  for (int mt = wave; mt < 5; mt += 4) {
    {
      uint2 z = {0u,0u};
      *(uint2*)&HsPs[(mt*16 + (lane>>2))*104 + 80 + (lane&3)*4] = z;
    }
    f32x4 sc[5];
    #pragma unroll
    for (int nt = 0; nt < 5; ++nt) {
      f32x4 a = {0.f,0.f,0.f,0.f};
      #pragma unroll
      for (int kt = 0; kt < 2; ++kt) {
        f16x8 af = *(const f16x8*)&Qs[(mt*16 + lc)*72 + kt*32 + lg*8];
        f16x8 bf = *(const f16x8*)&Ks[(nt*16 + lc)*72 + kt*32 + lg*8];
        a = MFMA(af, bf, a);
      }
      sc[nt] = a;
    }
    #pragma unroll
    for (int r = 0; r < 4; ++r) {
      float vals[5];
      #pragma unroll
      for (int nt = 0; nt < 5; ++nt) {
        float v = sc[nt][r]*0.125f;
        if (nt*16 + lc > 64) v = -1e30f;
        vals[nt] = v;
      }
      float mx = vals[0];
      #pragma unroll
      for (int nt = 1; nt < 5; ++nt) mx = fmaxf(mx, vals[nt]);
      #pragma unroll
      for (int o = 8; o >= 1; o >>= 1) mx = fmaxf(mx, __shfl_xor(mx, o, 16));
      float sum = 0.f, p[5];
      #pragma unroll
      for (int nt = 0; nt < 5; ++nt) { p[nt] = __expf(vals[nt]-mx); sum += p[nt]; }
      #pragma unroll
      for (int o = 8; o >= 1; o >>= 1) sum += __shfl_xor(sum, o, 16);
      float inv = 1.f/sum;
      int row = mt*16 + lg*4 + r;
      #pragma unroll
      for (int nt = 0; nt < 5; ++nt) HsPs[row*104 + nt*16 + lc] = (f16)(p[nt]*inv);
    }
    f32x4 oacc[4];
    #pragma unroll
    for (int nt = 0; nt < 4; ++nt) {
      f32x4 a = {0.f,0.f,0.f,0.f};
      #pragma unroll
      for (int kt = 0; kt < 3; ++kt) {
        f16x8 af = *(const f16x8*)&HsPs[(mt*16 + lc)*104 + kt*32 + lg*8];
        f16x8 bf = *(const f16x8*)&Vt[(nt*16 + lc)*104 + kt*32 + lg*8];
        a = MFMA(af, bf, a);
      }
      oacc[nt] = a;
    }
    float* xb = x + ((long)b*SEQL)*DMODEL + hd*DHEAD;
    #pragma unroll
    for (int nt = 0; nt < 4; ++nt) {
      #pragma unroll
      for (int r = 0; r < 4; ++r) {
        int s = mt*16 + lg*4 + r;
        if (s < SEQL) {
          int e = nt*16 + lc;
          xb[(long)s*DMODEL + e] += oacc[nt][r];
        }
      }
    }
  }
}

// ======== 256x256 8-phase-style GEMM (T2 swizzle + T3/T4 counted vmcnt + T5) ========
// C = A(MxK) * B(NxK)^T + bias.  ACT=0: gelu -> f16 out   ACT=1: += into f32 out
// 512 threads = 8 waves (2M x 4N). BK=32. Ring-4 LDS (distance-2 K-tile prefetch).
// LDS tile row = 32 f16 = 4 chunks of 16B; chunk swizzle kp' = kp ^ ((row>>1)&3),
// applied on the GLOBAL source (gload_lds dest stays linear) and on ds_read.
template<int ACT>
__global__ __launch_bounds__(512, 2) void gemm256(
    const f16* __restrict__ A, const f16* __restrict__ B,
    const float* __restrict__ bias, void* __restrict__ Cout,
    int M, int N, int K) {
  __shared__ __align__(16) f16 As[4][256*32];
  __shared__ __align__(16) f16 Bs[4][256*32];
  const int tid = threadIdx.x;
  const int wid = tid >> 6, lane = tid & 63;
  const int lrow = lane & 15, lk = lane >> 4;
  const int wr = wid >> 2, wc = wid & 3;

  // bijective XCD swizzle (m204)
  const int gx = gridDim.x;
  const int nwg = gx * gridDim.y;
  const int orig = blockIdx.y * gx + blockIdx.x;
  const int q = nwg >> 3, r = nwg & 7;
  const int xcd = orig & 7, lin = orig >> 3;
  const int wgid = (xcd < r ? xcd*(q+1) : r*(q+1) + (xcd - r)*q) + lin;
  const int bx = wgid % gx, by = wgid / gx;

  const long m0 = (long)by * 256, n0 = (long)bx * 256;

  f32x4 acc[8][4];
  #pragma unroll
  for (int i = 0; i < 8; ++i)
    #pragma unroll
    for (int j = 0; j < 4; ++j) acc[i][j] = (f32x4){0.f,0.f,0.f,0.f};

  const int NT = K >> 5;
  auto stageA = [&](int t) {
    const int s = t & 3;
    #pragma unroll
    for (int i = 0; i < 2; ++i) {
      int c = tid + i*512;                 // 1024 chunks of 16B
      int row = c >> 2;
      int kp = (c & 3) ^ ((row >> 1) & 3); // inverse-swizzled global source
      gload16(A + (m0 + row)*(long)K + t*32 + kp*8, &As[s][c*8]);
    }
  };
  auto stageB = [&](int t) {
    const int s = t & 3;
    #pragma unroll
    for (int i = 0; i < 2; ++i) {
      int c = tid + i*512;
      int row = c >> 2;
      int kp = (c & 3) ^ ((row >> 1) & 3);
      gload16(B + (n0 + row)*(long)K + t*32 + kp*8, &Bs[s][c*8]);
    }
  };

  stageA(0); stageB(0);
  if (NT > 1) { stageA(1); stageB(1); }

  for (int t = 0; t < NT; ++t) {
    const int s = t & 3;
    // gate: tile t fully in LDS; keep tile t+1's loads in flight (never drain mid-loop)
    if (t + 2 < NT) asm volatile("s_waitcnt vmcnt(4)" ::: "memory");
    else            asm volatile("s_waitcnt vmcnt(0)" ::: "memory");
    asm volatile("s_barrier" ::: "memory");

    // ---- phase 0: stage A(t+2) | read B-frags + A-frags(m0..3) | 16 MFMA ----
    if (t + 2 < NT) stageA(t + 2);
    f16x8 bf[4], af[4];
    #pragma unroll
    for (int nf = 0; nf < 4; ++nf) {
      int row = wc*64 + nf*16 + lrow;
      bf[nf] = *(const f16x8*)&Bs[s][row*32 + ((lk ^ ((row>>1)&3))*8)];
    }
    #pragma unroll
    for (int mf = 0; mf < 4; ++mf) {
      int row = wr*128 + mf*16 + lrow;
      af[mf] = *(const f16x8*)&As[s][row*32 + ((lk ^ ((row>>1)&3))*8)];
    }
    __builtin_amdgcn_s_setprio(1);
    #pragma unroll
    for (int mf = 0; mf < 4; ++mf)
      #pragma unroll
      for (int nf = 0; nf < 4; ++nf)
        acc[mf][nf] = MFMA(af[mf], bf[nf], acc[mf][nf]);
    __builtin_amdgcn_s_setprio(0);
    asm volatile("s_barrier" ::: "memory");

    // ---- phase 1: stage B(t+2) | read A-frags(m4..7) | 16 MFMA ----
    if (t + 2 < NT) stageB(t + 2);
    #pragma unroll
    for (int mf = 0; mf < 4; ++mf) {
      int row = wr*128 + 64 + mf*16 + lrow;
      af[mf] = *(const f16x8*)&As[s][row*32 + ((lk ^ ((row>>1)&3))*8)];
    }
    __builtin_amdgcn_s_setprio(1);
    #pragma unroll
    for (int mf = 0; mf < 4; ++mf)
      #pragma unroll
      for (int nf = 0; nf < 4; ++nf)
        acc[4+mf][nf] = MFMA(af[mf], bf[nf], acc[4+mf][nf]);
    __builtin_amdgcn_s_setprio(0);
    asm volatile("s_barrier" ::: "memory");
  }

  // ---- epilogue ----
  #pragma unroll
  for (int nf = 0; nf < 4; ++nf) {
    int col = (int)n0 + wc*64 + nf*16 + lrow;
    float bv = bias[col];
    #pragma unroll
    for (int mf = 0; mf < 8; ++mf) {
      #pragma unroll
      for (int r2 = 0; r2 < 4; ++r2) {
        long row = m0 + wr*128 + mf*16 + lk*4 + r2;
        float v = acc[mf][nf][r2] + bv;
        if (ACT == 0) {
          float g = 0.5f*v*(1.f + erff(v*0.70710678118654752f));
          ((f16*)Cout)[row*(long)N + col] = (f16)g;
        } else {
          ((float*)Cout)[row*(long)N + col] += v;
        }
      }
    }
  }
}

// ---------------- head: logits = cls @ head_w^T + b, softmax (all fp32) ----------------
__global__ __launch_bounds__(256) void head_kernel(
    const float* __restrict__ x, const float* __restrict__ hw,
    const float* __restrict__ hb, float* __restrict__ out) {
  const int b = blockIdx.x, tid = threadIdx.x;
  __shared__ float cls[768];
  __shared__ float red[8];
  const float* xr = x + (long)b*SEQL*DMODEL;
  #pragma unroll
  for (int j = 0; j < 3; ++j) cls[tid + j*256] = xr[tid + j*256];
  __syncthreads();
  float lgv[4];
  #pragma unroll
  for (int j = 0; j < 4; ++j) {
    int c = tid + j*256;
    float acc = -1e30f;
    if (c < 1000) {
      const float* wr = hw + (long)c*768;
      float s_ = 0.f;
      for (int i = 0; i < 768; ++i) s_ += cls[i]*wr[i];
      acc = s_ + hb[c];
    }
    lgv[j] = acc;
  }
  const int wave = tid>>6, lane = tid&63;
  float mx = fmaxf(fmaxf(lgv[0],lgv[1]),fmaxf(lgv[2],lgv[3]));
  #pragma unroll
  for (int o = 32; o >= 1; o >>= 1) mx = fmaxf(mx, __shfl_xor(mx, o));
  if (lane == 0) red[wave] = mx;
  __syncthreads();
  mx = fmaxf(fmaxf(red[0],red[1]),fmaxf(red[2],red[3]));
  float e[4]; float sum = 0.f;
  #pragma unroll
  for (int j = 0; j < 4; ++j) {
    int c = tid + j*256;
    e[j] = (c < 1000) ? expf(lgv[j]-mx) : 0.f;
    sum += e[j];
  }
  #pragma unroll
  for (int o = 32; o >= 1; o >>= 1) sum += __shfl_xor(sum, o);
  if (lane == 0) red[4+wave] = sum;
  __syncthreads();
  sum = red[4]+red[5]+red[6]+red[7];
  float inv = 1.f/sum;
  #pragma unroll
  for (int j = 0; j < 4; ++j) {
    int c = tid + j*256;
    if (c < 1000) out[(long)b*1000 + c] = e[j]*inv;
  }
}

extern "C" void kernel_launch(void* const* d_in, const int* in_sizes, int n_in,
                              void* d_out, int out_size, void* d_ws, size_t ws_size,
                              hipStream_t stream) {
  const float* images     = (const float*)d_in[0];
  const float* linear_w   = (const float*)d_in[1];
  const float* linear_b   = (const float*)d_in[2];
  const float* class_tok  = (const float*)d_in[3];
  const float* pos_emb    = (const float*)d_in[4];
  const float* ln1_g      = (const float*)d_in[5];
  const float* ln1_b      = (const float*)d_in[6];
  const float* wq         = (const float*)d_in[7];
  const float* bq         = (const float*)d_in[8];
  const float* wk         = (const float*)d_in[9];
  const float* bk         = (const float*)d_in[10];
  const float* wv         = (const float*)d_in[11];
  const float* bv         = (const float*)d_in[12];
  const float* ln2_g      = (const float*)d_in[13];
  const float* ln2_b      = (const float*)d_in[14];
  const float* w1         = (const float*)d_in[15];
  const float* b1         = (const float*)d_in[16];
  const float* w2         = (const float*)d_in[17];
  const float* b2         = (const float*)d_in[18];
  const float* head_w     = (const float*)d_in[19];
  const float* head_b     = (const float*)d_in[20];

  char* ws = (char*)d_ws;
  float* xbuf = (float*)(ws + 0);            // 16640*768 f32   = 51,118,080
  f16*   hbuf = (f16*)(ws + 51118080);       // 16640*768 f16   = 25,559,040
  f16*   mbuf = (f16*)(ws + 76677120);       // 16640*3072 f16  = 102,236,160
  // big layout: all-layer w1/w2 fp16 upfront
  f16*   w1all = (f16*)(ws + 178913280);     // 12*3072*768 f16 = 56,623,104
  f16*   w2all = (f16*)(ws + 235536384);     // 56,623,104
  f16*   wqbB  = (f16*)(ws + 292159488);     // 1,179,648
  f16*   wkbB  = (f16*)(ws + 293339136);
  f16*   wvbB  = (f16*)(ws + 294518784);     // end 295,698,432
  // small layout (fallback): per-layer slots
  f16*   w1b  = (f16*)(ws + 178913280);
  f16*   w2b  = (f16*)(ws + 183631872);
  f16*   wqbS = (f16*)(ws + 188350464);
  f16*   wkbS = (f16*)(ws + 189530112);
  f16*   wvbS = (f16*)(ws + 190709760);      // end 191,889,408
  if (ws_size < 191889408ull) return;
  const bool big = ws_size >= 295698432ull;
  f16* wqb = big ? wqbB : wqbS;
  f16* wkb = big ? wkbB : wkbS;
  f16* wvb = big ? wvbB : wvbS;

  patch_embed<<<dim3(SEQL, NBATCH), 256, 0, stream>>>(images, linear_w, linear_b,
                                                      class_tok, pos_emb, xbuf);
  cvt_f16k<<<576, 256, 0, stream>>>(wq, wqb, 589824);
  cvt_f16k<<<576, 256, 0, stream>>>(wk, wkb, 589824);
  cvt_f16k<<<576, 256, 0, stream>>>(wv, wvb, 589824);
  if (big) {
    cvt_f16k<<<27648, 256, 0, stream>>>(w1, w1all, 28311552);
    cvt_f16k<<<27648, 256, 0, stream>>>(w2, w2all, 28311552);
  }

  for (int l = 0; l < NLAYER; ++l) {
    ln_kernel<<<MTOK, 256, 0, stream>>>(xbuf, ln1_g + l*768, ln1_b + l*768, hbuf);
    attn_kernel<<<dim3(NHEAD, NBATCH), 256, 0, stream>>>(
        hbuf, wqb + l*49152, wkb + l*49152, wvb + l*49152,
        bq + l*768, bk + l*768, bv + l*768, xbuf);
    ln_kernel<<<MTOK, 256, 0, stream>>>(xbuf, ln2_g + l*768, ln2_b + l*768, hbuf);
    f16* w1p = big ? (w1all + (long)l*2359296) : w1b;
    f16* w2p = big ? (w2all + (long)l*2359296) : w2b;
    if (!big) cvt_f16k<<<2304, 256, 0, stream>>>(w1 + (long)l*2359296, w1b, 2359296);
    gemm256<0><<<dim3(MLPD/256, MTOK/256), 512, 0, stream>>>(
        hbuf, w1p, b1 + l*3072, (void*)mbuf, MTOK, MLPD, DMODEL);
    if (!big) cvt_f16k<<<2304, 256, 0, stream>>>(w2 + (long)l*2359296, w2b, 2359296);
    gemm256<1><<<dim3(DMODEL/256, MTOK/256), 512, 0, stream>>>(
        mbuf, w2p, b2 + l*768, (void*)xbuf, MTOK, DMODEL, MLPD);
  }
  head_kernel<<<NBATCH, 256, 0, stream>>>(xbuf, head_w, head_b, (float*)d_out);
}

// Round 4
// 4874.532 us; speedup vs baseline: 1.2332x; 1.2332x over previous
//
#include <hip/hip_runtime.h>

#define NLAYER 12
#define NHEAD  12
#define DHEAD  64
#define DMODEL 768
#define SEQL   65
#define NBATCH 256
#define MTOK   (NBATCH*SEQL)   // 16640
#define MLPD   3072

typedef _Float16 f16;
typedef f16  f16x8 __attribute__((ext_vector_type(8)));
typedef f16  f16x4 __attribute__((ext_vector_type(4)));
typedef float f32x4 __attribute__((ext_vector_type(4)));

#define MFMA(a,b,c) __builtin_amdgcn_mfma_f32_16x16x32_f16(a,b,c,0,0,0)

__device__ __forceinline__ void gload16(const void* g, void* l) {
  __builtin_amdgcn_global_load_lds((const __attribute__((address_space(1))) void*)g,
                                   (__attribute__((address_space(3))) void*)l, 16, 0, 0);
}

// fast erf-based exact-GELU: A&S 7.1.26, abs err < 1.5e-7 (<< f16 rounding)
__device__ __forceinline__ float gelu_f(float v) {
  float z = fabsf(v) * 0.70710678118654752f;
  float t = 1.f / (1.f + 0.3275911f * z);
  float p = ((((1.061405429f*t - 1.453152027f)*t + 1.421413741f)*t
              - 0.284496736f)*t + 0.254829592f)*t;
  float erfz = 1.f - p * __expf(-z*z);
  float erfv = copysignf(erfz, v);
  return 0.5f * v * (1.f + erfv);
}

// ---------------- fp32 -> fp16 convert ----------------
__global__ __launch_bounds__(256) void cvt_f16k(const float* __restrict__ in,
                                                f16* __restrict__ out, int n) {
  long i = ((long)blockIdx.x*256 + threadIdx.x)*4;
  if (i >= n) return;
  const float4 v = *(const float4*)(in + i);
  f16x4 o = { (f16)v.x, (f16)v.y, (f16)v.z, (f16)v.w };
  *(f16x4*)(out + i) = o;
}

// ---------------- patch embed + cls + pos ----------------
__global__ __launch_bounds__(256) void patch_embed(
    const float* __restrict__ images, const float* __restrict__ lw,
    const float* __restrict__ lb, const float* __restrict__ cls,
    const float* __restrict__ pe, float* __restrict__ x) {
  const int s = blockIdx.x, n = blockIdx.y, tid = threadIdx.x;
  __shared__ float p[16];
  if (s > 0 && tid < 16) p[tid] = images[(long)n*1024 + (s-1)*16 + tid];
  __syncthreads();
  float* xr = x + ((long)n*SEQL + s)*DMODEL;
  #pragma unroll
  for (int j = 0; j < 3; ++j) {
    int d = tid + j*256;
    float v;
    if (s == 0) {
      v = cls[d] + pe[d];
    } else {
      float acc = lb[d];
      #pragma unroll
      for (int i = 0; i < 16; ++i) acc += p[i]*lw[d*16+i];
      v = acc + pe[s*DMODEL + d];
    }
    xr[d] = v;
  }
}

// ---------------- LayerNorm (fp32 in, fp16 out) ----------------
__global__ __launch_bounds__(256) void ln_kernel(
    const float* __restrict__ x, const float* __restrict__ g,
    const float* __restrict__ b, f16* __restrict__ out) {
  const int row = blockIdx.x, tid = threadIdx.x;
  const float* xr = x + (long)row*DMODEL;
  float v0 = xr[tid], v1 = xr[tid+256], v2 = xr[tid+512];
  float s = v0+v1+v2;
  float s2 = v0*v0 + v1*v1 + v2*v2;
  #pragma unroll
  for (int o = 32; o >= 1; o >>= 1) { s += __shfl_xor(s, o); s2 += __shfl_xor(s2, o); }
  __shared__ float red[8];
  const int wave = tid>>6, lane = tid&63;
  if (lane == 0) { red[wave] = s; red[4+wave] = s2; }
  __syncthreads();
  s  = red[0]+red[1]+red[2]+red[3];
  s2 = red[4]+red[5]+red[6]+red[7];
  float mean = s * (1.f/768.f);
  float var  = s2 * (1.f/768.f) - mean*mean;
  float rstd = rsqrtf(var + 1e-5f);
  f16* orow = out + (long)row*DMODEL;
  orow[tid]     = (f16)((v0-mean)*rstd*g[tid]     + b[tid]);
  orow[tid+256] = (f16)((v1-mean)*rstd*g[tid+256] + b[tid+256]);
  orow[tid+512] = (f16)((v2-mean)*rstd*g[tid+512] + b[tid+512]);
}

// ---------------- fused per-(b,head) QKV + attention, x += o ----------------
__global__ __launch_bounds__(256) void attn_kernel(
    const f16* __restrict__ h, const f16* __restrict__ wq, const f16* __restrict__ wk,
    const f16* __restrict__ wv, const float* __restrict__ bq, const float* __restrict__ bk,
    const float* __restrict__ bv, float* __restrict__ x) {
  __shared__ __align__(16) f16 HsPs[80*104];
  __shared__ __align__(16) f16 Qs[80*72];
  __shared__ __align__(16) f16 Ks[80*72];
  __shared__ __align__(16) f16 Vt[64*104];
  const int hd = blockIdx.x, b = blockIdx.y;
  const int tid = threadIdx.x, wave = tid>>6, lane = tid&63;
  const int lc = lane & 15, lg = lane >> 4;
  const f16* hbase = h + ((long)b*SEQL)*DMODEL + hd*DHEAD;

  for (int c = tid; c < 80*8; c += 256) {
    int s = c >> 3, ec = (c & 7)*8;
    uint4 val = {0u,0u,0u,0u};
    if (s < SEQL) val = *(const uint4*)(hbase + (long)s*DMODEL + ec);
    *(uint4*)&HsPs[s*104 + ec] = val;
  }
  for (int c = tid; c < 64*104/8; c += 256) {
    uint4 z = {0u,0u,0u,0u};
    *(uint4*)&Vt[c*8] = z;
  }
  __syncthreads();

  for (int task = wave; task < 15; task += 4) {
    int mat = task / 5, mt = task % 5;
    const f16* W = (mat == 0 ? wq : mat == 1 ? wk : wv) + hd*DHEAD*DHEAD;
    const float* bias = (mat == 0 ? bq : mat == 1 ? bk : bv) + hd*DHEAD;
    #pragma unroll
    for (int nt = 0; nt < 4; ++nt) {
      f32x4 a = {0.f,0.f,0.f,0.f};
      #pragma unroll
      for (int kt = 0; kt < 2; ++kt) {
        f16x8 af = *(const f16x8*)&HsPs[(mt*16 + lc)*104 + kt*32 + lg*8];
        f16x8 bf = *(const f16x8*)&W[(nt*16 + lc)*DHEAD + kt*32 + lg*8];
        a = MFMA(af, bf, a);
      }
      float bb = bias[nt*16 + lc];
      #pragma unroll
      for (int r = 0; r < 4; ++r) {
        int s = mt*16 + lg*4 + r;
        int e = nt*16 + lc;
        float v = a[r] + bb;
        if (mat == 0)      Qs[s*72 + e] = (f16)v;
        else if (mat == 1) Ks[s*72 + e] = (f16)v;
        else               Vt[e*104 + s] = (f16)v;
      }
    }
  }
  __syncthreads();

  for (int mt = wave; mt < 5; mt += 4) {
    {
      uint2 z = {0u,0u};
      *(uint2*)&HsPs[(mt*16 + (lane>>2))*104 + 80 + (lane&3)*4] = z;
    }
    f32x4 sc[5];
    #pragma unroll
    for (int nt = 0; nt < 5; ++nt) {
      f32x4 a = {0.f,0.f,0.f,0.f};
      #pragma unroll
      for (int kt = 0; kt < 2; ++kt) {
        f16x8 af = *(const f16x8*)&Qs[(mt*16 + lc)*72 + kt*32 + lg*8];
        f16x8 bf = *(const f16x8*)&Ks[(nt*16 + lc)*72 + kt*32 + lg*8];
        a = MFMA(af, bf, a);
      }
      sc[nt] = a;
    }
    #pragma unroll
    for (int r = 0; r < 4; ++r) {
      float vals[5];
      #pragma unroll
      for (int nt = 0; nt < 5; ++nt) {
        float v = sc[nt][r]*0.125f;
        if (nt*16 + lc > 64) v = -1e30f;
        vals[nt] = v;
      }
      float mx = vals[0];
      #pragma unroll
      for (int nt = 1; nt < 5; ++nt) mx = fmaxf(mx, vals[nt]);
      #pragma unroll
      for (int o = 8; o >= 1; o >>= 1) mx = fmaxf(mx, __shfl_xor(mx, o, 16));
      float sum = 0.f, p[5];
      #pragma unroll
      for (int nt = 0; nt < 5; ++nt) { p[nt] = __expf(vals[nt]-mx); sum += p[nt]; }
      #pragma unroll
      for (int o = 8; o >= 1; o >>= 1) sum += __shfl_xor(sum, o, 16);
      float inv = 1.f/sum;
      int row = mt*16 + lg*4 + r;
      #pragma unroll
      for (int nt = 0; nt < 5; ++nt) HsPs[row*104 + nt*16 + lc] = (f16)(p[nt]*inv);
    }
    f32x4 oacc[4];
    #pragma unroll
    for (int nt = 0; nt < 4; ++nt) {
      f32x4 a = {0.f,0.f,0.f,0.f};
      #pragma unroll
      for (int kt = 0; kt < 3; ++kt) {
        f16x8 af = *(const f16x8*)&HsPs[(mt*16 + lc)*104 + kt*32 + lg*8];
        f16x8 bf = *(const f16x8*)&Vt[(nt*16 + lc)*104 + kt*32 + lg*8];
        a = MFMA(af, bf, a);
      }
      oacc[nt] = a;
    }
    float* xb = x + ((long)b*SEQL)*DMODEL + hd*DHEAD;
    #pragma unroll
    for (int nt = 0; nt < 4; ++nt) {
      #pragma unroll
      for (int r = 0; r < 4; ++r) {
        int s = mt*16 + lg*4 + r;
        if (s < SEQL) {
          int e = nt*16 + lc;
          xb[(long)s*DMODEL + e] += oacc[nt][r];
        }
      }
    }
  }
}

// ======== 256x256 GEMM: ring-4 LDS, distance-3 prefetch, counted vmcnt, T2+T5 ========
// C = A(MxK) * B(NxK)^T + bias.  ACT=0: gelu -> f16 (LDS-restaged coalesced stores)
//                                ACT=1: += into f32 out (full-line scalar stores)
template<int ACT>
__global__ __launch_bounds__(512, 2) void gemm256(
    const f16* __restrict__ A, const f16* __restrict__ B,
    const float* __restrict__ bias, void* __restrict__ Cout,
    int M, int N, int K) {
  // 131072 B: ring slots As[s]=lds+s*8192, Bs[s]=lds+32768+s*8192 (f16 units);
  // epilogue (ACT=0) reuses all of it as the 256x256 f16 C-tile.
  __shared__ __align__(16) f16 lds[65536];
  const int tid = threadIdx.x;
  const int wid = tid >> 6, lane = tid & 63;
  const int lrow = lane & 15, lk = lane >> 4;
  const int wr = wid >> 2, wc = wid & 3;

  // bijective XCD swizzle (m204)
  const int gx = gridDim.x;
  const int nwg = gx * gridDim.y;
  const int orig = blockIdx.y * gx + blockIdx.x;
  const int q = nwg >> 3, r = nwg & 7;
  const int xcd = orig & 7, lin = orig >> 3;
  const int wgid = (xcd < r ? xcd*(q+1) : r*(q+1) + (xcd - r)*q) + lin;
  const int bx = wgid % gx, by = wgid / gx;

  const long m0 = (long)by * 256, n0 = (long)bx * 256;

  f32x4 acc[8][4];
  #pragma unroll
  for (int i = 0; i < 8; ++i)
    #pragma unroll
    for (int j = 0; j < 4; ++j) acc[i][j] = (f32x4){0.f,0.f,0.f,0.f};

  const int NT = K >> 5;
  auto stageA = [&](int t) {
    f16* As = &lds[(t & 3)*8192];
    #pragma unroll
    for (int i = 0; i < 2; ++i) {
      int c = tid + i*512;                 // 1024 chunks of 16B
      int row = c >> 2;
      int kp = (c & 3) ^ ((row >> 1) & 3); // inverse-swizzled global source
      gload16(A + (m0 + row)*(long)K + t*32 + kp*8, &As[c*8]);
    }
  };
  auto stageB = [&](int t) {
    f16* Bs = &lds[32768 + (t & 3)*8192];
    #pragma unroll
    for (int i = 0; i < 2; ++i) {
      int c = tid + i*512;
      int row = c >> 2;
      int kp = (c & 3) ^ ((row >> 1) & 3);
      gload16(B + (n0 + row)*(long)K + t*32 + kp*8, &Bs[c*8]);
    }
  };

  stageA(0); stageB(0);
  stageA(1); stageB(1);
  stageA(2); stageB(2);

  for (int t = 0; t < NT; ++t) {
    const f16* As = &lds[(t & 3)*8192];
    const f16* Bs = &lds[32768 + (t & 3)*8192];
    // gate: tile t fully in LDS; keep tiles t+1,t+2 in flight (never drain mid-loop)
    {
      int rem = NT - 1 - t;
      if (rem >= 2)      asm volatile("s_waitcnt vmcnt(8)" ::: "memory");
      else if (rem == 1) asm volatile("s_waitcnt vmcnt(4)" ::: "memory");
      else               asm volatile("s_waitcnt vmcnt(0)" ::: "memory");
    }
    asm volatile("s_barrier" ::: "memory");

    // ---- phase 0: stage A(t+3) | read B-frags + A-frags(m0..3) | 16 MFMA ----
    if (t + 3 < NT) stageA(t + 3);
    f16x8 bf[4], af[4];
    #pragma unroll
    for (int nf = 0; nf < 4; ++nf) {
      int row = wc*64 + nf*16 + lrow;
      bf[nf] = *(const f16x8*)&Bs[row*32 + ((lk ^ ((row>>1)&3))*8)];
    }
    #pragma unroll
    for (int mf = 0; mf < 4; ++mf) {
      int row = wr*128 + mf*16 + lrow;
      af[mf] = *(const f16x8*)&As[row*32 + ((lk ^ ((row>>1)&3))*8)];
    }
    __builtin_amdgcn_s_setprio(1);
    #pragma unroll
    for (int mf = 0; mf < 4; ++mf)
      #pragma unroll
      for (int nf = 0; nf < 4; ++nf)
        acc[mf][nf] = MFMA(af[mf], bf[nf], acc[mf][nf]);
    __builtin_amdgcn_s_setprio(0);
    asm volatile("s_barrier" ::: "memory");

    // ---- phase 1: stage B(t+3) | read A-frags(m4..7) | 16 MFMA ----
    if (t + 3 < NT) stageB(t + 3);
    #pragma unroll
    for (int mf = 0; mf < 4; ++mf) {
      int row = wr*128 + 64 + mf*16 + lrow;
      af[mf] = *(const f16x8*)&As[row*32 + ((lk ^ ((row>>1)&3))*8)];
    }
    __builtin_amdgcn_s_setprio(1);
    #pragma unroll
    for (int mf = 0; mf < 4; ++mf)
      #pragma unroll
      for (int nf = 0; nf < 4; ++nf)
        acc[4+mf][nf] = MFMA(af[mf], bf[nf], acc[4+mf][nf]);
    __builtin_amdgcn_s_setprio(0);
    asm volatile("s_barrier" ::: "memory");
  }

  // ---- epilogue ----
  if (ACT == 0) {
    // gelu(acc+bias) -> swizzled LDS C-tile -> coalesced f16x8 full-line stores
    #pragma unroll
    for (int nf = 0; nf < 4; ++nf) {
      int col = wc*64 + nf*16 + lrow;
      float bv = bias[(int)n0 + col];
      #pragma unroll
      for (int mf = 0; mf < 8; ++mf) {
        #pragma unroll
        for (int r2 = 0; r2 < 4; ++r2) {
          int row = wr*128 + mf*16 + lk*4 + r2;
          float v = acc[mf][nf][r2] + bv;
          int byte = (row*512 + col*2) ^ (((row>>2)&3)<<5);
          *(f16*)((char*)lds + byte) = (f16)gelu_f(v);
        }
      }
    }
    asm volatile("s_barrier" ::: "memory");
    f16* Cf = (f16*)Cout;
    #pragma unroll
    for (int i = 0; i < 16; ++i) {
      int g = i*512 + tid;
      int row = g >> 5, c5 = g & 31;
      int byte = (row*512 + c5*16) ^ (((row>>2)&3)<<5);
      f16x8 val = *(const f16x8*)((const char*)lds + byte);
      *(f16x8*)(Cf + (m0 + row)*(long)N + n0 + c5*8) = val;
    }
  } else {
    float* Cf = (float*)Cout;
    #pragma unroll
    for (int nf = 0; nf < 4; ++nf) {
      int col = (int)n0 + wc*64 + nf*16 + lrow;
      float bv = bias[col];
      #pragma unroll
      for (int mf = 0; mf < 8; ++mf) {
        #pragma unroll
        for (int r2 = 0; r2 < 4; ++r2) {
          long row = m0 + wr*128 + mf*16 + lk*4 + r2;
          Cf[row*(long)N + col] += acc[mf][nf][r2] + bv;
        }
      }
    }
  }
}

// ---------------- head: logits = cls @ head_w^T + b, softmax (all fp32) ----------------
__global__ __launch_bounds__(256) void head_kernel(
    const float* __restrict__ x, const float* __restrict__ hw,
    const float* __restrict__ hb, float* __restrict__ out) {
  const int b = blockIdx.x, tid = threadIdx.x;
  __shared__ float cls[768];
  __shared__ float red[8];
  const float* xr = x + (long)b*SEQL*DMODEL;
  #pragma unroll
  for (int j = 0; j < 3; ++j) cls[tid + j*256] = xr[tid + j*256];
  __syncthreads();
  float lgv[4];
  #pragma unroll
  for (int j = 0; j < 4; ++j) {
    int c = tid + j*256;
    float acc = -1e30f;
    if (c < 1000) {
      const float* wr = hw + (long)c*768;
      float s_ = 0.f;
      for (int i = 0; i < 768; ++i) s_ += cls[i]*wr[i];
      acc = s_ + hb[c];
    }
    lgv[j] = acc;
  }
  const int wave = tid>>6, lane = tid&63;
  float mx = fmaxf(fmaxf(lgv[0],lgv[1]),fmaxf(lgv[2],lgv[3]));
  #pragma unroll
  for (int o = 32; o >= 1; o >>= 1) mx = fmaxf(mx, __shfl_xor(mx, o));
  if (lane == 0) red[wave] = mx;
  __syncthreads();
  mx = fmaxf(fmaxf(red[0],red[1]),fmaxf(red[2],red[3]));
  float e[4]; float sum = 0.f;
  #pragma unroll
  for (int j = 0; j < 4; ++j) {
    int c = tid + j*256;
    e[j] = (c < 1000) ? expf(lgv[j]-mx) : 0.f;
    sum += e[j];
  }
  #pragma unroll
  for (int o = 32; o >= 1; o >>= 1) sum += __shfl_xor(sum, o);
  if (lane == 0) red[4+wave] = sum;
  __syncthreads();
  sum = red[4]+red[5]+red[6]+red[7];
  float inv = 1.f/sum;
  #pragma unroll
  for (int j = 0; j < 4; ++j) {
    int c = tid + j*256;
    if (c < 1000) out[(long)b*1000 + c] = e[j]*inv;
  }
}

extern "C" void kernel_launch(void* const* d_in, const int* in_sizes, int n_in,
                              void* d_out, int out_size, void* d_ws, size_t ws_size,
                              hipStream_t stream) {
  const float* images     = (const float*)d_in[0];
  const float* linear_w   = (const float*)d_in[1];
  const float* linear_b   = (const float*)d_in[2];
  const float* class_tok  = (const float*)d_in[3];
  const float* pos_emb    = (const float*)d_in[4];
  const float* ln1_g      = (const float*)d_in[5];
  const float* ln1_b      = (const float*)d_in[6];
  const float* wq         = (const float*)d_in[7];
  const float* bq         = (const float*)d_in[8];
  const float* wk         = (const float*)d_in[9];
  const float* bk         = (const float*)d_in[10];
  const float* wv         = (const float*)d_in[11];
  const float* bv         = (const float*)d_in[12];
  const float* ln2_g      = (const float*)d_in[13];
  const float* ln2_b      = (const float*)d_in[14];
  const float* w1         = (const float*)d_in[15];
  const float* b1         = (const float*)d_in[16];
  const float* w2         = (const float*)d_in[17];
  const float* b2         = (const float*)d_in[18];
  const float* head_w     = (const float*)d_in[19];
  const float* head_b     = (const float*)d_in[20];

  char* ws = (char*)d_ws;
  float* xbuf = (float*)(ws + 0);            // 16640*768 f32   = 51,118,080
  f16*   hbuf = (f16*)(ws + 51118080);       // 16640*768 f16   = 25,559,040
  f16*   mbuf = (f16*)(ws + 76677120);       // 16640*3072 f16  = 102,236,160
  // big layout: all-layer w1/w2 fp16 upfront
  f16*   w1all = (f16*)(ws + 178913280);     // 12*3072*768 f16 = 56,623,104
  f16*   w2all = (f16*)(ws + 235536384);     // 56,623,104
  f16*   wqbB  = (f16*)(ws + 292159488);     // 1,179,648
  f16*   wkbB  = (f16*)(ws + 293339136);
  f16*   wvbB  = (f16*)(ws + 294518784);     // end 295,698,432
  // small layout (fallback): per-layer slots
  f16*   w1b  = (f16*)(ws + 178913280);
  f16*   w2b  = (f16*)(ws + 183631872);
  f16*   wqbS = (f16*)(ws + 188350464);
  f16*   wkbS = (f16*)(ws + 189530112);
  f16*   wvbS = (f16*)(ws + 190709760);      // end 191,889,408
  if (ws_size < 191889408ull) return;
  const bool big = ws_size >= 295698432ull;
  f16* wqb = big ? wqbB : wqbS;
  f16* wkb = big ? wkbB : wkbS;
  f16* wvb = big ? wvbB : wvbS;

  patch_embed<<<dim3(SEQL, NBATCH), 256, 0, stream>>>(images, linear_w, linear_b,
                                                      class_tok, pos_emb, xbuf);
  cvt_f16k<<<576, 256, 0, stream>>>(wq, wqb, 589824);
  cvt_f16k<<<576, 256, 0, stream>>>(wk, wkb, 589824);
  cvt_f16k<<<576, 256, 0, stream>>>(wv, wvb, 589824);
  if (big) {
    cvt_f16k<<<27648, 256, 0, stream>>>(w1, w1all, 28311552);
    cvt_f16k<<<27648, 256, 0, stream>>>(w2, w2all, 28311552);
  }

  for (int l = 0; l < NLAYER; ++l) {
    ln_kernel<<<MTOK, 256, 0, stream>>>(xbuf, ln1_g + l*768, ln1_b + l*768, hbuf);
    attn_kernel<<<dim3(NHEAD, NBATCH), 256, 0, stream>>>(
        hbuf, wqb + l*49152, wkb + l*49152, wvb + l*49152,
        bq + l*768, bk + l*768, bv + l*768, xbuf);
    ln_kernel<<<MTOK, 256, 0, stream>>>(xbuf, ln2_g + l*768, ln2_b + l*768, hbuf);
    f16* w1p = big ? (w1all + (long)l*2359296) : w1b;
    f16* w2p = big ? (w2all + (long)l*2359296) : w2b;
    if (!big) cvt_f16k<<<2304, 256, 0, stream>>>(w1 + (long)l*2359296, w1b, 2359296);
    gemm256<0><<<dim3(MLPD/256, MTOK/256), 512, 0, stream>>>(
        hbuf, w1p, b1 + l*3072, (void*)mbuf, MTOK, MLPD, DMODEL);
    if (!big) cvt_f16k<<<2304, 256, 0, stream>>>(w2 + (long)l*2359296, w2b, 2359296);
    gemm256<1><<<dim3(DMODEL/256, MTOK/256), 512, 0, stream>>>(
        mbuf, w2p, b2 + l*768, (void*)xbuf, MTOK, DMODEL, MLPD);
  }
  head_kernel<<<NBATCH, 256, 0, stream>>>(xbuf, head_w, head_b, (float*)d_out);
}

// Round 5
// 4706.128 us; speedup vs baseline: 1.2774x; 1.0358x over previous
//
#include <hip/hip_runtime.h>

#define NLAYER 12
#define NHEAD  12
#define DHEAD  64
#define DMODEL 768
#define SEQL   65
#define NBATCH 256
#define MTOK   (NBATCH*SEQL)   // 16640
#define MLPD   3072

typedef _Float16 f16;
typedef f16  f16x8 __attribute__((ext_vector_type(8)));
typedef f16  f16x4 __attribute__((ext_vector_type(4)));
typedef float f32x4 __attribute__((ext_vector_type(4)));

#define MFMA(a,b,c) __builtin_amdgcn_mfma_f32_16x16x32_f16(a,b,c,0,0,0)

__device__ __forceinline__ void gload16(const void* g, void* l) {
  __builtin_amdgcn_global_load_lds((const __attribute__((address_space(1))) void*)g,
                                   (__attribute__((address_space(3))) void*)l, 16, 0, 0);
}

// fast erf-based exact-GELU: A&S 7.1.26, abs err < 1.5e-7 (<< f16 rounding)
__device__ __forceinline__ float gelu_f(float v) {
  float z = fabsf(v) * 0.70710678118654752f;
  float t = 1.f / (1.f + 0.3275911f * z);
  float p = ((((1.061405429f*t - 1.453152027f)*t + 1.421413741f)*t
              - 0.284496736f)*t + 0.254829592f)*t;
  float erfz = 1.f - p * __expf(-z*z);
  float erfv = copysignf(erfz, v);
  return 0.5f * v * (1.f + erfv);
}

// ---------------- fp32 -> fp16 convert ----------------
__global__ __launch_bounds__(256) void cvt_f16k(const float* __restrict__ in,
                                                f16* __restrict__ out, int n) {
  long i = ((long)blockIdx.x*256 + threadIdx.x)*4;
  if (i >= n) return;
  const float4 v = *(const float4*)(in + i);
  f16x4 o = { (f16)v.x, (f16)v.y, (f16)v.z, (f16)v.w };
  *(f16x4*)(out + i) = o;
}

// ---------------- patch embed + cls + pos ----------------
__global__ __launch_bounds__(256) void patch_embed(
    const float* __restrict__ images, const float* __restrict__ lw,
    const float* __restrict__ lb, const float* __restrict__ cls,
    const float* __restrict__ pe, float* __restrict__ x) {
  const int s = blockIdx.x, n = blockIdx.y, tid = threadIdx.x;
  __shared__ float p[16];
  if (s > 0 && tid < 16) p[tid] = images[(long)n*1024 + (s-1)*16 + tid];
  __syncthreads();
  float* xr = x + ((long)n*SEQL + s)*DMODEL;
  #pragma unroll
  for (int j = 0; j < 3; ++j) {
    int d = tid + j*256;
    float v;
    if (s == 0) {
      v = cls[d] + pe[d];
    } else {
      float acc = lb[d];
      #pragma unroll
      for (int i = 0; i < 16; ++i) acc += p[i]*lw[d*16+i];
      v = acc + pe[s*DMODEL + d];
    }
    xr[d] = v;
  }
}

// ---------------- LayerNorm (fp32 in, fp16 out) ----------------
__global__ __launch_bounds__(256) void ln_kernel(
    const float* __restrict__ x, const float* __restrict__ g,
    const float* __restrict__ b, f16* __restrict__ out) {
  const int row = blockIdx.x, tid = threadIdx.x;
  const float* xr = x + (long)row*DMODEL;
  float v0 = xr[tid], v1 = xr[tid+256], v2 = xr[tid+512];
  float s = v0+v1+v2;
  float s2 = v0*v0 + v1*v1 + v2*v2;
  #pragma unroll
  for (int o = 32; o >= 1; o >>= 1) { s += __shfl_xor(s, o); s2 += __shfl_xor(s2, o); }
  __shared__ float red[8];
  const int wave = tid>>6, lane = tid&63;
  if (lane == 0) { red[wave] = s; red[4+wave] = s2; }
  __syncthreads();
  s  = red[0]+red[1]+red[2]+red[3];
  s2 = red[4]+red[5]+red[6]+red[7];
  float mean = s * (1.f/768.f);
  float var  = s2 * (1.f/768.f) - mean*mean;
  float rstd = rsqrtf(var + 1e-5f);
  f16* orow = out + (long)row*DMODEL;
  orow[tid]     = (f16)((v0-mean)*rstd*g[tid]     + b[tid]);
  orow[tid+256] = (f16)((v1-mean)*rstd*g[tid+256] + b[tid+256]);
  orow[tid+512] = (f16)((v2-mean)*rstd*g[tid+512] + b[tid+512]);
}

// ---------------- fused per-(b,head) QKV + attention, x += o ----------------
__global__ __launch_bounds__(256) void attn_kernel(
    const f16* __restrict__ h, const f16* __restrict__ wq, const f16* __restrict__ wk,
    const f16* __restrict__ wv, const float* __restrict__ bq, const float* __restrict__ bk,
    const float* __restrict__ bv, float* __restrict__ x) {
  __shared__ __align__(16) f16 HsPs[80*104];
  __shared__ __align__(16) f16 Qs[80*72];
  __shared__ __align__(16) f16 Ks[80*72];
  __shared__ __align__(16) f16 Vt[64*104];
  const int hd = blockIdx.x, b = blockIdx.y;
  const int tid = threadIdx.x, wave = tid>>6, lane = tid&63;
  const int lc = lane & 15, lg = lane >> 4;
  const f16* hbase = h + ((long)b*SEQL)*DMODEL + hd*DHEAD;

  for (int c = tid; c < 80*8; c += 256) {
    int s = c >> 3, ec = (c & 7)*8;
    uint4 val = {0u,0u,0u,0u};
    if (s < SEQL) val = *(const uint4*)(hbase + (long)s*DMODEL + ec);
    *(uint4*)&HsPs[s*104 + ec] = val;
  }
  for (int c = tid; c < 64*104/8; c += 256) {
    uint4 z = {0u,0u,0u,0u};
    *(uint4*)&Vt[c*8] = z;
  }
  __syncthreads();

  for (int task = wave; task < 15; task += 4) {
    int mat = task / 5, mt = task % 5;
    const f16* W = (mat == 0 ? wq : mat == 1 ? wk : wv) + hd*DHEAD*DHEAD;
    const float* bias = (mat == 0 ? bq : mat == 1 ? bk : bv) + hd*DHEAD;
    #pragma unroll
    for (int nt = 0; nt < 4; ++nt) {
      f32x4 a = {0.f,0.f,0.f,0.f};
      #pragma unroll
      for (int kt = 0; kt < 2; ++kt) {
        f16x8 af = *(const f16x8*)&HsPs[(mt*16 + lc)*104 + kt*32 + lg*8];
        f16x8 bf = *(const f16x8*)&W[(nt*16 + lc)*DHEAD + kt*32 + lg*8];
        a = MFMA(af, bf, a);
      }
      float bb = bias[nt*16 + lc];
      #pragma unroll
      for (int r = 0; r < 4; ++r) {
        int s = mt*16 + lg*4 + r;
        int e = nt*16 + lc;
        float v = a[r] + bb;
        if (mat == 0)      Qs[s*72 + e] = (f16)v;
        else if (mat == 1) Ks[s*72 + e] = (f16)v;
        else               Vt[e*104 + s] = (f16)v;
      }
    }
  }
  __syncthreads();

  for (int mt = wave; mt < 5; mt += 4) {
    {
      uint2 z = {0u,0u};
      *(uint2*)&HsPs[(mt*16 + (lane>>2))*104 + 80 + (lane&3)*4] = z;
    }
    f32x4 sc[5];
    #pragma unroll
    for (int nt = 0; nt < 5; ++nt) {
      f32x4 a = {0.f,0.f,0.f,0.f};
      #pragma unroll
      for (int kt = 0; kt < 2; ++kt) {
        f16x8 af = *(const f16x8*)&Qs[(mt*16 + lc)*72 + kt*32 + lg*8];
        f16x8 bf = *(const f16x8*)&Ks[(nt*16 + lc)*72 + kt*32 + lg*8];
        a = MFMA(af, bf, a);
      }
      sc[nt] = a;
    }
    #pragma unroll
    for (int r = 0; r < 4; ++r) {
      float vals[5];
      #pragma unroll
      for (int nt = 0; nt < 5; ++nt) {
        float v = sc[nt][r]*0.125f;
        if (nt*16 + lc > 64) v = -1e30f;
        vals[nt] = v;
      }
      float mx = vals[0];
      #pragma unroll
      for (int nt = 1; nt < 5; ++nt) mx = fmaxf(mx, vals[nt]);
      #pragma unroll
      for (int o = 8; o >= 1; o >>= 1) mx = fmaxf(mx, __shfl_xor(mx, o, 16));
      float sum = 0.f, p[5];
      #pragma unroll
      for (int nt = 0; nt < 5; ++nt) { p[nt] = __expf(vals[nt]-mx); sum += p[nt]; }
      #pragma unroll
      for (int o = 8; o >= 1; o >>= 1) sum += __shfl_xor(sum, o, 16);
      float inv = 1.f/sum;
      int row = mt*16 + lg*4 + r;
      #pragma unroll
      for (int nt = 0; nt < 5; ++nt) HsPs[row*104 + nt*16 + lc] = (f16)(p[nt]*inv);
    }
    f32x4 oacc[4];
    #pragma unroll
    for (int nt = 0; nt < 4; ++nt) {
      f32x4 a = {0.f,0.f,0.f,0.f};
      #pragma unroll
      for (int kt = 0; kt < 3; ++kt) {
        f16x8 af = *(const f16x8*)&HsPs[(mt*16 + lc)*104 + kt*32 + lg*8];
        f16x8 bf = *(const f16x8*)&Vt[(nt*16 + lc)*104 + kt*32 + lg*8];
        a = MFMA(af, bf, a);
      }
      oacc[nt] = a;
    }
    float* xb = x + ((long)b*SEQL)*DMODEL + hd*DHEAD;
    #pragma unroll
    for (int nt = 0; nt < 4; ++nt) {
      #pragma unroll
      for (int r = 0; r < 4; ++r) {
        int s = mt*16 + lg*4 + r;
        if (s < SEQL) {
          int e = nt*16 + lc;
          xb[(long)s*DMODEL + e] += oacc[nt][r];
        }
      }
    }
  }
}

// ======== 128x128 GEMM: ring-3 LDS, distance-2 prefetch, counted vmcnt, 3 blocks/CU ====
// C = A(MxK) * B(NxK)^T + bias.  ACT=0: gelu -> f16 (LDS-restaged coalesced stores)
//                                ACT=1: += into f32 out (full-line stores)
// Single barrier per K-tile (ring-3 distance-2 makes stage(t+2) race-free: readers of
// that slot finished tile t-1 before arriving at this tile's barrier).
template<int ACT>
__global__ __launch_bounds__(256, 3) void gemm128(
    const f16* __restrict__ A, const f16* __restrict__ B,
    const float* __restrict__ bias, void* __restrict__ Cout,
    int M, int N, int K) {
  // 48 KB: As[s]=lds+s*4096, Bs[s]=lds+12288+s*4096 (f16 units).
  // Epilogue (ACT=0) reuses first 32 KB as the 128x128 f16 C-tile.
  __shared__ __align__(16) f16 lds[24576];
  const int tid = threadIdx.x;
  const int wave = tid >> 6, lane = tid & 63;
  const int lrow = lane & 15, lk = lane >> 4;
  const int wm = (wave >> 1) * 64, wn = (wave & 1) * 64;

  // bijective XCD swizzle (m204)
  const int gx = gridDim.x;
  const int nwg = gx * gridDim.y;
  const int orig = blockIdx.y * gx + blockIdx.x;
  const int q = nwg >> 3, r = nwg & 7;
  const int xcd = orig & 7, lin = orig >> 3;
  const int wgid = (xcd < r ? xcd*(q+1) : r*(q+1) + (xcd - r)*q) + lin;
  const int bx = wgid % gx, by = wgid / gx;

  const long m0 = (long)by * 128, n0 = (long)bx * 128;

  f32x4 acc[4][4];
  #pragma unroll
  for (int i = 0; i < 4; ++i)
    #pragma unroll
    for (int j = 0; j < 4; ++j) acc[i][j] = (f32x4){0.f,0.f,0.f,0.f};

  const int NT = K >> 5;
  auto stage = [&](int t) {
    const int s = t % 3;
    f16* As = &lds[s*4096];
    f16* Bs = &lds[12288 + s*4096];
    #pragma unroll
    for (int i = 0; i < 2; ++i) {
      int c = tid + i*256;                 // 512 chunks of 16B per matrix
      int row = c >> 2;
      int kp = (c & 3) ^ ((row >> 1) & 3); // inverse-swizzled global source
      gload16(A + (m0 + row)*(long)K + t*32 + kp*8, &As[c*8]);
      gload16(B + (n0 + row)*(long)K + t*32 + kp*8, &Bs[c*8]);
    }
  };
  stage(0); stage(1);

  for (int t = 0; t < NT; ++t) {
    const int s = t % 3;
    const f16* As = &lds[s*4096];
    const f16* Bs = &lds[12288 + s*4096];
    // wait for tile t's own 4 loads; keep tile t+1's 4 in flight
    if (t + 1 < NT) asm volatile("s_waitcnt vmcnt(4)" ::: "memory");
    else            asm volatile("s_waitcnt vmcnt(0)" ::: "memory");
    asm volatile("s_barrier" ::: "memory");   // all waves' tile-t loads now in LDS
    if (t + 2 < NT) stage(t + 2);
    f16x8 af[4], bfr[4];
    #pragma unroll
    for (int mf = 0; mf < 4; ++mf) {
      int row = wm + mf*16 + lrow;
      af[mf] = *(const f16x8*)&As[row*32 + ((lk ^ ((row>>1)&3))*8)];
    }
    #pragma unroll
    for (int nf = 0; nf < 4; ++nf) {
      int row = wn + nf*16 + lrow;
      bfr[nf] = *(const f16x8*)&Bs[row*32 + ((lk ^ ((row>>1)&3))*8)];
    }
    __builtin_amdgcn_s_setprio(1);
    #pragma unroll
    for (int mf = 0; mf < 4; ++mf)
      #pragma unroll
      for (int nf = 0; nf < 4; ++nf)
        acc[mf][nf] = MFMA(af[mf], bfr[nf], acc[mf][nf]);
    __builtin_amdgcn_s_setprio(0);
  }

  __syncthreads();   // all waves done with last tile before LDS reuse / exit

  if (ACT == 0) {
    // gelu(acc+bias) -> swizzled LDS C-tile -> coalesced f16x8 full-line stores
    #pragma unroll
    for (int nf = 0; nf < 4; ++nf) {
      int col = wn + nf*16 + lrow;
      float bv = bias[(int)n0 + col];
      #pragma unroll
      for (int mf = 0; mf < 4; ++mf) {
        #pragma unroll
        for (int r2 = 0; r2 < 4; ++r2) {
          int row = wm + mf*16 + lk*4 + r2;
          float v = acc[mf][nf][r2] + bv;
          int byte = (row*256 + col*2) ^ (((row>>2)&7)<<4);
          *(f16*)((char*)lds + byte) = (f16)gelu_f(v);
        }
      }
    }
    __syncthreads();
    f16* Cf = (f16*)Cout;
    #pragma unroll
    for (int i = 0; i < 8; ++i) {
      int g = i*256 + tid;
      int row = g >> 4, ch = g & 15;
      int byte = (row*256 + ch*16) ^ (((row>>2)&7)<<4);
      f16x8 val = *(const f16x8*)((const char*)lds + byte);
      *(f16x8*)(Cf + (m0 + row)*(long)N + n0 + ch*8) = val;
    }
  } else {
    float* Cf = (float*)Cout;
    #pragma unroll
    for (int nf = 0; nf < 4; ++nf) {
      int col = (int)n0 + wn + nf*16 + lrow;
      float bv = bias[col];
      #pragma unroll
      for (int mf = 0; mf < 4; ++mf) {
        #pragma unroll
        for (int r2 = 0; r2 < 4; ++r2) {
          long row = m0 + wm + mf*16 + lk*4 + r2;
          Cf[row*(long)N + col] += acc[mf][nf][r2] + bv;
        }
      }
    }
  }
}

// ---------------- head: logits = cls @ head_w^T + b, softmax (all fp32) ----------------
__global__ __launch_bounds__(256) void head_kernel(
    const float* __restrict__ x, const float* __restrict__ hw,
    const float* __restrict__ hb, float* __restrict__ out) {
  const int b = blockIdx.x, tid = threadIdx.x;
  __shared__ float cls[768];
  __shared__ float red[8];
  const float* xr = x + (long)b*SEQL*DMODEL;
  #pragma unroll
  for (int j = 0; j < 3; ++j) cls[tid + j*256] = xr[tid + j*256];
  __syncthreads();
  float lgv[4];
  #pragma unroll
  for (int j = 0; j < 4; ++j) {
    int c = tid + j*256;
    float acc = -1e30f;
    if (c < 1000) {
      const float* wr = hw + (long)c*768;
      float s_ = 0.f;
      for (int i = 0; i < 768; ++i) s_ += cls[i]*wr[i];
      acc = s_ + hb[c];
    }
    lgv[j] = acc;
  }
  const int wave = tid>>6, lane = tid&63;
  float mx = fmaxf(fmaxf(lgv[0],lgv[1]),fmaxf(lgv[2],lgv[3]));
  #pragma unroll
  for (int o = 32; o >= 1; o >>= 1) mx = fmaxf(mx, __shfl_xor(mx, o));
  if (lane == 0) red[wave] = mx;
  __syncthreads();
  mx = fmaxf(fmaxf(red[0],red[1]),fmaxf(red[2],red[3]));
  float e[4]; float sum = 0.f;
  #pragma unroll
  for (int j = 0; j < 4; ++j) {
    int c = tid + j*256;
    e[j] = (c < 1000) ? expf(lgv[j]-mx) : 0.f;
    sum += e[j];
  }
  #pragma unroll
  for (int o = 32; o >= 1; o >>= 1) sum += __shfl_xor(sum, o);
  if (lane == 0) red[4+wave] = sum;
  __syncthreads();
  sum = red[4]+red[5]+red[6]+red[7];
  float inv = 1.f/sum;
  #pragma unroll
  for (int j = 0; j < 4; ++j) {
    int c = tid + j*256;
    if (c < 1000) out[(long)b*1000 + c] = e[j]*inv;
  }
}

extern "C" void kernel_launch(void* const* d_in, const int* in_sizes, int n_in,
                              void* d_out, int out_size, void* d_ws, size_t ws_size,
                              hipStream_t stream) {
  const float* images     = (const float*)d_in[0];
  const float* linear_w   = (const float*)d_in[1];
  const float* linear_b   = (const float*)d_in[2];
  const float* class_tok  = (const float*)d_in[3];
  const float* pos_emb    = (const float*)d_in[4];
  const float* ln1_g      = (const float*)d_in[5];
  const float* ln1_b      = (const float*)d_in[6];
  const float* wq         = (const float*)d_in[7];
  const float* bq         = (const float*)d_in[8];
  const float* wk         = (const float*)d_in[9];
  const float* bk         = (const float*)d_in[10];
  const float* wv         = (const float*)d_in[11];
  const float* bv         = (const float*)d_in[12];
  const float* ln2_g      = (const float*)d_in[13];
  const float* ln2_b      = (const float*)d_in[14];
  const float* w1         = (const float*)d_in[15];
  const float* b1         = (const float*)d_in[16];
  const float* w2         = (const float*)d_in[17];
  const float* b2         = (const float*)d_in[18];
  const float* head_w     = (const float*)d_in[19];
  const float* head_b     = (const float*)d_in[20];

  char* ws = (char*)d_ws;
  float* xbuf = (float*)(ws + 0);            // 16640*768 f32   = 51,118,080
  f16*   hbuf = (f16*)(ws + 51118080);       // 16640*768 f16   = 25,559,040
  f16*   mbuf = (f16*)(ws + 76677120);       // 16640*3072 f16  = 102,236,160
  // big layout: all-layer w1/w2 fp16 upfront
  f16*   w1all = (f16*)(ws + 178913280);     // 12*3072*768 f16 = 56,623,104
  f16*   w2all = (f16*)(ws + 235536384);     // 56,623,104
  f16*   wqbB  = (f16*)(ws + 292159488);     // 1,179,648
  f16*   wkbB  = (f16*)(ws + 293339136);
  f16*   wvbB  = (f16*)(ws + 294518784);     // end 295,698,432
  // small layout (fallback): per-layer slots
  f16*   w1b  = (f16*)(ws + 178913280);
  f16*   w2b  = (f16*)(ws + 183631872);
  f16*   wqbS = (f16*)(ws + 188350464);
  f16*   wkbS = (f16*)(ws + 189530112);
  f16*   wvbS = (f16*)(ws + 190709760);      // end 191,889,408
  if (ws_size < 191889408ull) return;
  const bool big = ws_size >= 295698432ull;
  f16* wqb = big ? wqbB : wqbS;
  f16* wkb = big ? wkbB : wkbS;
  f16* wvb = big ? wvbB : wvbS;

  patch_embed<<<dim3(SEQL, NBATCH), 256, 0, stream>>>(images, linear_w, linear_b,
                                                      class_tok, pos_emb, xbuf);
  cvt_f16k<<<576, 256, 0, stream>>>(wq, wqb, 589824);
  cvt_f16k<<<576, 256, 0, stream>>>(wk, wkb, 589824);
  cvt_f16k<<<576, 256, 0, stream>>>(wv, wvb, 589824);
  if (big) {
    cvt_f16k<<<27648, 256, 0, stream>>>(w1, w1all, 28311552);
    cvt_f16k<<<27648, 256, 0, stream>>>(w2, w2all, 28311552);
  }

  for (int l = 0; l < NLAYER; ++l) {
    ln_kernel<<<MTOK, 256, 0, stream>>>(xbuf, ln1_g + l*768, ln1_b + l*768, hbuf);
    attn_kernel<<<dim3(NHEAD, NBATCH), 256, 0, stream>>>(
        hbuf, wqb + l*49152, wkb + l*49152, wvb + l*49152,
        bq + l*768, bk + l*768, bv + l*768, xbuf);
    ln_kernel<<<MTOK, 256, 0, stream>>>(xbuf, ln2_g + l*768, ln2_b + l*768, hbuf);
    f16* w1p = big ? (w1all + (long)l*2359296) : w1b;
    f16* w2p = big ? (w2all + (long)l*2359296) : w2b;
    if (!big) cvt_f16k<<<2304, 256, 0, stream>>>(w1 + (long)l*2359296, w1b, 2359296);
    gemm128<0><<<dim3(MLPD/128, MTOK/128), 256, 0, stream>>>(
        hbuf, w1p, b1 + l*3072, (void*)mbuf, MTOK, MLPD, DMODEL);
    if (!big) cvt_f16k<<<2304, 256, 0, stream>>>(w2 + (long)l*2359296, w2b, 2359296);
    gemm128<1><<<dim3(DMODEL/128, MTOK/128), 256, 0, stream>>>(
        mbuf, w2p, b2 + l*768, (void*)xbuf, MTOK, DMODEL, MLPD);
  }
  head_kernel<<<NBATCH, 256, 0, stream>>>(xbuf, head_w, head_b, (float*)d_out);
}